// Round 1
// 723.159 us; speedup vs baseline: 1.0833x; 1.0833x over previous
//
#include <hip/hip_runtime.h>

typedef float floatx4 __attribute__((ext_vector_type(4)));
typedef short short8 __attribute__((ext_vector_type(8)));

#define H 768
#define NMENT 4096
#define TOTALP 131072
#define MAXK 64
#define BM 256
#define BN 256
#define BK 64
#define LDA_S 72   // shorts per A row in LDS: 64 data + 8 pad (144B rows, 16B aligned, conflict-free reads)

__device__ __forceinline__ unsigned short f32_to_bf16(float f) {
    unsigned int u = __builtin_bit_cast(unsigned int, f);
    u = u + 0x7FFFu + ((u >> 16) & 1u);   // round-to-nearest-even
    return (unsigned short)(u >> 16);
}

__device__ __forceinline__ short8 pack8(float4 a, float4 b) {
    short8 r;
    r[0] = (short)f32_to_bf16(a.x); r[1] = (short)f32_to_bf16(a.y);
    r[2] = (short)f32_to_bf16(a.z); r[3] = (short)f32_to_bf16(a.w);
    r[4] = (short)f32_to_bf16(b.x); r[5] = (short)f32_to_bf16(b.y);
    r[6] = (short)f32_to_bf16(b.z); r[7] = (short)f32_to_bf16(b.w);
    return r;
}

__device__ __forceinline__ void glds16(const unsigned short* g, unsigned short* l) {
    __builtin_amdgcn_global_load_lds(
        (const __attribute__((address_space(1))) unsigned int*)g,
        (__attribute__((address_space(3))) unsigned int*)l, 16, 0, 0);
}

// K0: W1 [1536 x 768] row-major -> BtA[n][k] = W1[k][n] (k<768), BtB[n][k] = W1[768+k][n], bf16
__global__ void k0_transpose(const float* __restrict__ W1,
                             unsigned short* __restrict__ BtA,
                             unsigned short* __restrict__ BtB) {
    __shared__ float tile[32][33];
    const int k0 = blockIdx.x * 32;
    const int n0 = blockIdx.y * 32;
    const int tx = threadIdx.x;
    const int ty = threadIdx.y;
#pragma unroll
    for (int i = 0; i < 4; ++i)
        tile[ty + i * 8][tx] = W1[(k0 + ty + i * 8) * H + n0 + tx];
    __syncthreads();
    unsigned short* dst = (k0 < H) ? BtA : BtB;
    const int kb = (k0 >= H) ? (k0 - H) : k0;
#pragma unroll
    for (int i = 0; i < 4; ++i) {
        const int n = n0 + ty + i * 8;
        dst[n * H + kb + tx] = f32_to_bf16(tile[tx][ty + i * 8]);
    }
}

// K3: out[n][j] = 0.5*faiss[n][j] for j<64, nota for j==64 (b2 added by nsplit==0 k2 blocks)
__global__ void k3_init_out(const float* __restrict__ faiss,
                            const float* __restrict__ nota,
                            float* __restrict__ out) {
    const int i = blockIdx.x * 256 + threadIdx.x;
    if (i < NMENT * (MAXK + 1)) {
        const int n = i / (MAXK + 1);
        const int j = i - n * (MAXK + 1);
        out[i] = (j < MAXK) ? 0.5f * faiss[n * MAXK + j] : nota[0];
    }
}

// Core GEMM: C[t0..t0+255][n0..n0+255] = A(rows, fp32, cast bf16) @ Bt^T (bf16 [n][k])
// Pipelined (T3-minimum + T14): double-buffered LDS; per K-step issue next-tile loads
// BEFORE computing current tile; single barrier per K-step.
// MODE 0: epilogue writes M = acc + b1  (outp = M, w2s holds b1 chunk)
// MODE 1: epilogue: h = acc + M[mention], relu, dot W2-chunk, reduce, atomicAdd to out
template<int MODE>
__global__ __launch_bounds__(1024, 4)
void gemm_core(const float* __restrict__ A, const unsigned short* __restrict__ Bt,
               const float* __restrict__ M, const float* __restrict__ W2,
               const float* __restrict__ b2, const int* __restrict__ mention_idx,
               const int* __restrict__ col_idx, const float* __restrict__ b1,
               float* __restrict__ outp) {
    __shared__ unsigned short ldsA[2 * BM * LDA_S];  // 2 x 36864 B, padded rows
    __shared__ unsigned short ldsB[2 * BN * BK];     // 2 x 32768 B, XOR-swizzled chunks
    __shared__ float w2s[BN];                        // W2 chunk (MODE 1) or b1 chunk (MODE 0)
    __shared__ float scoreBuf[BM * 4];

    const int bid = blockIdx.x;
    int t_tile, nsplit;
    if (MODE == 1) {
        // group blocks so the 3 n-splits of a t-tile land on the same XCD (bid%8 round-robin)
        const int g = bid / 24, rr = bid % 24;
        t_tile = g * 8 + (rr & 7);
        nsplit = rr >> 3;
    } else {
        t_tile = bid % 16;
        nsplit = bid / 16;
    }
    const int t0 = t_tile * BM;
    const int n0 = nsplit * BN;

    const int tid = threadIdx.x;
    const int lane = tid & 63;
    const int w = tid >> 6;           // 16 waves: 4x4 grid of 64x64 wave tiles
    const int wm = w >> 2, wn = w & 3;
    const int l15 = lane & 15, quad = lane >> 4;

    if (tid < BN) w2s[tid] = (MODE == 1) ? W2[n0 + tid] : b1[n0 + tid];

    floatx4 acc[4][4];
#pragma unroll
    for (int mi = 0; mi < 4; ++mi)
#pragma unroll
        for (int ni = 0; ni < 4; ++ni)
            acc[mi][ni] = floatx4{0.f, 0.f, 0.f, 0.f};

    // A staging map: 4 threads per row, 16 floats (64B) each
    const int arow = tid >> 2;
    const int aseg = tid & 3;
    const float* agp = A + (size_t)(t0 + arow) * H + aseg * 16;
    const int aoff = arow * LDA_S + aseg * 16;

// -- compute one BK tile from buffer CUR: 2 k32 steps, 16 MFMAs each --
#define COMPUTE_TILE(CUR)                                                                 \
    do {                                                                                  \
        const unsigned short* lA = ldsA + (CUR) * (BM * LDA_S);                           \
        const unsigned short* lB = ldsB + (CUR) * (BN * BK);                              \
        _Pragma("unroll")                                                                 \
        for (int ks = 0; ks < 2; ++ks) {                                                  \
            short8 a[4], b[4];                                                            \
            _Pragma("unroll")                                                             \
            for (int mi = 0; mi < 4; ++mi)                                                \
                a[mi] = *(const short8*)&lA[(wm * 64 + mi * 16 + l15) * LDA_S + ks * 32 + quad * 8]; \
            _Pragma("unroll")                                                             \
            for (int ni = 0; ni < 4; ++ni) {                                              \
                const int nr = wn * 64 + ni * 16 + l15;                                   \
                const int slot = (quad + ks * 4) ^ (nr & 7);                              \
                b[ni] = *(const short8*)&lB[nr * BK + slot * 8];                          \
            }                                                                             \
            _Pragma("unroll")                                                             \
            for (int mi = 0; mi < 4; ++mi)                                                \
                _Pragma("unroll")                                                         \
                for (int ni = 0; ni < 4; ++ni)                                            \
                    acc[mi][ni] = __builtin_amdgcn_mfma_f32_16x16x32_bf16(a[mi], b[ni], acc[mi][ni], 0, 0, 0); \
        }                                                                                 \
    } while (0)

    // ---- prologue: stage tile 0 into buffer 0 ----
    {
        float4 v0 = *(const float4*)(agp);
        float4 v1 = *(const float4*)(agp + 4);
        float4 v2 = *(const float4*)(agp + 8);
        float4 v3 = *(const float4*)(agp + 12);
#pragma unroll
        for (int i = 0; i < 2; ++i) {
            const int br = w * 16 + i * 8;          // wave-uniform base row
            const int r = br + (lane >> 3);
            const int cd = (lane & 7) ^ (r & 7);    // data chunk for this slot
            glds16(Bt + (size_t)(n0 + r) * H + cd * 8, &ldsB[br * BK]);
        }
        *(short8*)(&ldsA[aoff]) = pack8(v0, v1);
        *(short8*)(&ldsA[aoff + 8]) = pack8(v2, v3);
        __syncthreads();
    }

    int cur = 0;
    // ---- main loop: prefetch tile(kc) while computing tile(kc-BK) ----
    for (int kc = BK; kc < H; kc += BK) {
        // 1. issue next-tile A loads into registers (latency hides under MFMA phase)
        float4 v0 = *(const float4*)(agp + kc);
        float4 v1 = *(const float4*)(agp + kc + 4);
        float4 v2 = *(const float4*)(agp + kc + 8);
        float4 v3 = *(const float4*)(agp + kc + 12);
        // 2. issue next-tile B global_load_lds into the other buffer
        unsigned short* lbn = ldsB + (cur ^ 1) * (BN * BK);
#pragma unroll
        for (int i = 0; i < 2; ++i) {
            const int br = w * 16 + i * 8;
            const int r = br + (lane >> 3);
            const int cd = (lane & 7) ^ (r & 7);
            glds16(Bt + (size_t)(n0 + r) * H + kc + cd * 8, lbn + br * BK);
        }
        // 3. compute current tile
        COMPUTE_TILE(cur);
        // 4. pack + write A into the other buffer (loads have landed by now)
        unsigned short* lan = ldsA + (cur ^ 1) * (BM * LDA_S);
        *(short8*)(&lan[aoff]) = pack8(v0, v1);
        *(short8*)(&lan[aoff + 8]) = pack8(v2, v3);
        // 5. single barrier per K-step (drains glds + orders ds_writes)
        __syncthreads();
        cur ^= 1;
    }
    // ---- final tile: compute only ----
    COMPUTE_TILE(cur);
#undef COMPUTE_TILE

    if (MODE == 0) {
        // write M = acc + b1
#pragma unroll
        for (int ni = 0; ni < 4; ++ni) {
            const int nl = wn * 64 + ni * 16 + l15;
            const float bv = w2s[nl];
#pragma unroll
            for (int mi = 0; mi < 4; ++mi)
#pragma unroll
                for (int r = 0; r < 4; ++r) {
                    const int row = t0 + wm * 64 + mi * 16 + quad * 4 + r;
                    outp[(size_t)row * H + n0 + nl] = acc[mi][ni][r] + bv;
                }
        }
    } else {
        // h = acc + M[mention]; relu; dot with W2 chunk; reduce; atomicAdd
#pragma unroll
        for (int mi = 0; mi < 4; ++mi) {
#pragma unroll
            for (int r = 0; r < 4; ++r) {
                const int rl = wm * 64 + mi * 16 + quad * 4 + r;
                const int m = mention_idx[t0 + rl];
                const float* Mrow = M + (size_t)m * H + n0;
                float s = 0.f;
#pragma unroll
                for (int ni = 0; ni < 4; ++ni) {
                    const int nl = wn * 64 + ni * 16 + l15;
                    const float v = acc[mi][ni][r] + Mrow[nl];
                    s = fmaf(fmaxf(v, 0.f), w2s[nl], s);
                }
                s += __shfl_xor(s, 1, 64);
                s += __shfl_xor(s, 2, 64);
                s += __shfl_xor(s, 4, 64);
                s += __shfl_xor(s, 8, 64);
                if (l15 == 0) scoreBuf[rl * 4 + wn] = s;
            }
        }
        __syncthreads();
        if (tid < BM) {
            const int t = t0 + tid;
            float tot = scoreBuf[tid * 4] + scoreBuf[tid * 4 + 1] +
                        scoreBuf[tid * 4 + 2] + scoreBuf[tid * 4 + 3];
            if (nsplit == 0) tot += b2[0];
            atomicAdd(&outp[(size_t)mention_idx[t] * (MAXK + 1) + col_idx[t]], tot);
        }
    }
}

extern "C" void kernel_launch(void* const* d_in, const int* in_sizes, int n_in,
                              void* d_out, int out_size, void* d_ws, size_t ws_size,
                              hipStream_t stream) {
    const float* ment  = (const float*)d_in[0];
    const float* cand  = (const float*)d_in[1];
    const float* W1    = (const float*)d_in[2];
    const float* b1    = (const float*)d_in[3];
    const float* W2    = (const float*)d_in[4];
    const float* b2    = (const float*)d_in[5];
    const float* faiss = (const float*)d_in[6];
    const float* nota  = (const float*)d_in[7];
    const int* mention_idx = (const int*)d_in[8];
    const int* col_idx = (const int*)d_in[9];
    float* out = (float*)d_out;

    // ws: BtA bf16 [768*768] | BtB bf16 [768*768] | M fp32 [4096*768]  (~14.9 MB)
    unsigned short* BtA = (unsigned short*)d_ws;
    unsigned short* BtB = BtA + H * H;
    float* M = (float*)(BtB + H * H);

    k0_transpose<<<dim3(48, 24), dim3(32, 8), 0, stream>>>(W1, BtA, BtB);
    k3_init_out<<<(NMENT * (MAXK + 1) + 255) / 256, 256, 0, stream>>>(faiss, nota, out);
    // K1: M[4096x768] = ment @ W1a + b1 : 16 t-tiles x 3 n-splits
    gemm_core<0><<<48, 1024, 0, stream>>>(ment, BtA, nullptr, nullptr, nullptr,
                                          nullptr, nullptr, b1, M);
    // K2: 512 t-tiles x 3 n-splits, XCD-grouped
    gemm_core<1><<<1536, 1024, 0, stream>>>(cand, BtB, M, W2, b2,
                                            mention_idx, col_idx, nullptr, out);
}